// Round 1
// 3017.192 us; speedup vs baseline: 1.5750x; 1.5750x over previous
//
#include <hip/hip_runtime.h>
#include <hip/hip_bf16.h>
#include <math.h>

// GRU encoder: B=32, T=512, V=32000, H=1024, reset_after=True, mask_zero=True.
//
// R3 redesign of the recurrence sync: the old flag+release/acquire handshake
// cost >=3 serialized device RTs + buffer_wbl2 + buffer_inv per step (8us/step,
// MfmaUtil 1%). Now h is exchanged as SELF-VALIDATING u64 atoms:
//   word = (tag32 << 32) | (bf16 h[2u+1] << 16) | bf16 h[2u],  tag(h(t)) = t+2
// stored/loaded with RELAXED agent-scope atomics (bypass non-coherent L1/L2).
// No fences, no flags, no vmcnt drains on the publish path: one L3 round trip
// carries validity AND data. Exact-tag match => double-buffer race-free and
// immune to poisoned (0xAA) or zeroed workspace. P is double-buffered in LDS
// => ONE __syncthreads per step. out stores are nontemporal, off all paths.

#define B_  32
#define T_  512
#define H_  1024
#define H3  3072
#define NG  64     // recurrence workgroups
#define UPG 16     // hidden units per wg

typedef short short8 __attribute__((ext_vector_type(8)));
typedef float float4_ __attribute__((ext_vector_type(4)));
typedef int   int4_  __attribute__((ext_vector_type(4)));
typedef unsigned short u16;
typedef unsigned long long ull;

__device__ __forceinline__ float bf2f(u16 u) {
  union { unsigned i; float f; } v; v.i = ((unsigned)u) << 16; return v.f;
}
__device__ __forceinline__ u16 f2bf(float f) {   // round-to-nearest-even
  union { float f; unsigned i; } v; v.f = f;
  unsigned r = v.i + 0x7FFFu + ((v.i >> 16) & 1u);
  return (u16)(r >> 16);
}
__device__ __forceinline__ float ldf(const void* p, size_t i, int f32) {
  return f32 ? ((const float*)p)[i] : bf2f(((const u16*)p)[i]);
}
// 8 consecutive elements -> bf16 bits
__device__ __forceinline__ short8 ld8(const void* base, size_t off, int f32) {
  short8 r;
  if (f32) {
    const float* p = (const float*)base + off;
    float4_ a = *(const float4_*)p;
    float4_ b = *(const float4_*)(p + 4);
    r[0]=(short)f2bf(a[0]); r[1]=(short)f2bf(a[1]); r[2]=(short)f2bf(a[2]); r[3]=(short)f2bf(a[3]);
    r[4]=(short)f2bf(b[0]); r[5]=(short)f2bf(b[1]); r[6]=(short)f2bf(b[2]); r[7]=(short)f2bf(b[3]);
  } else {
    r = *(const short8*)((const u16*)base + off);
  }
  return r;
}

__device__ __forceinline__ ull atomLD(const ull* p) {
  return __hip_atomic_load((ull*)p, __ATOMIC_RELAXED, __HIP_MEMORY_SCOPE_AGENT);
}
__device__ __forceinline__ void atomST(ull* p, ull v) {
  __hip_atomic_store(p, v, __ATOMIC_RELAXED, __HIP_MEMORY_SCOPE_AGENT);
}
__device__ __forceinline__ ull packh(unsigned tag, float h0, float h1) {
  return ((ull)tag << 32) | ((ull)f2bf(h1) << 16) | (ull)f2bf(h0);
}

// ------------------------------------------------------- Kd: dtype detect + canon
// Low u16 of each u32 word: fp32 -> uniform mantissa bits, P(bits[14:7]>=128)~0.5;
// packed bf16 -> a valid ~N(0,0.02) bf16, exponent field < 128 always.
__global__ __launch_bounds__(256) void detect_norm(
    const void* __restrict__ emb, const void* __restrict__ bias,
    int* dflag, float* __restrict__ bias_c) {
  __shared__ int cnt;
  __shared__ int sflag;
  if (threadIdx.x == 0) cnt = 0;
  __syncthreads();
  const unsigned* e = (const unsigned*)emb;
  const unsigned lo = e[threadIdx.x] & 0xFFFFu;
  if (((lo >> 7) & 0xFFu) >= 128u) atomicAdd(&cnt, 1);
  __syncthreads();
  if (threadIdx.x == 0) {
    sflag = (cnt > 32) ? 1 : 0;    // fp32 ~128 hits, bf16-packed ~0
    *dflag = sflag;
  }
  __syncthreads();
  const int f32 = sflag;
  for (int i = threadIdx.x; i < 2 * H3; i += 256) bias_c[i] = ldf(bias, i, f32);
}

// ---------------------------------------------------------------- K0: transpose
// [1024][3072] -> [3072][1024] canonical bf16, for both W and R. 32x32 tiles.
__global__ __launch_bounds__(256) void transpose_kernel(
    const void* __restrict__ W, const void* __restrict__ R,
    u16* __restrict__ Wt, u16* __restrict__ Rt, const int* dflag) {
  __shared__ u16 tile[32][33];
  const int f32 = *dflag;
  const void* src = blockIdx.z ? R : W;
  u16* dst = blockIdx.z ? Rt : Wt;
  int k0 = blockIdx.x * 32, n0 = blockIdx.y * 32;
  int c = threadIdx.x & 31, r8 = threadIdx.x >> 5;
  for (int rr = r8; rr < 32; rr += 8)
    tile[rr][c] = f2bf(ldf(src, (size_t)(k0 + rr) * H3 + n0 + c, f32));
  __syncthreads();
  for (int rr = r8; rr < 32; rr += 8)
    dst[(size_t)(n0 + rr) * H_ + k0 + c] = tile[c][rr];
}

// ---------------------------------------------------------------- K1: gx GEMM
// Tile: 128 rows (32 b x 4 t) x 128 n, BK=64. 4 waves, each 64x64 via 4x4 MFMA.
__global__ __launch_bounds__(256) void gx_gemm(
    const int* __restrict__ x, const void* __restrict__ emb,
    const u16* __restrict__ Wt, const float* __restrict__ bias_c,
    u16* __restrict__ gx, const int* dflag) {
  __shared__ u16 Al[128][72];   // A[m][k], +8 pad
  __shared__ u16 Bl[128][72];   // B^T: [n][k]
  __shared__ int tok[128];
  const int f32 = *dflag;
  const int tid = threadIdx.x;
  const int n0 = blockIdx.x * 128;
  const int t0 = blockIdx.y * 4;
  if (tid < 128) { int b = tid >> 2, dt = tid & 3; tok[tid] = x[b * T_ + t0 + dt]; }
  __syncthreads();
  const int lane = tid & 63, w = tid >> 6;
  const int l = lane & 15, q = lane >> 4;
  const int wm = w >> 1, wn = w & 1;
  float4_ acc[4][4];
  for (int i = 0; i < 4; i++) for (int j = 0; j < 4; j++) acc[i][j] = (float4_)0.0f;
  const int row = tid >> 1, half = tid & 1;
  for (int k0 = 0; k0 < H_; k0 += 64) {
    const size_t offA = (size_t)tok[row] * H_ + k0 + half * 32;
    const u16* srcB = Wt + (size_t)(n0 + row) * H_ + k0 + half * 32;
#pragma unroll
    for (int c = 0; c < 4; c++) {
      *(short8*)&Al[row][half * 32 + c * 8] = ld8(emb, offA + c * 8, f32);
      *(short8*)&Bl[row][half * 32 + c * 8] = *(const short8*)(srcB + c * 8);
    }
    __syncthreads();
#pragma unroll
    for (int ks = 0; ks < 2; ks++) {
      const int kk = ks * 32 + q * 8;
      short8 af[4], bfv[4];
#pragma unroll
      for (int mi = 0; mi < 4; mi++) af[mi] = *(const short8*)&Al[wm * 64 + mi * 16 + l][kk];
#pragma unroll
      for (int ni = 0; ni < 4; ni++) bfv[ni] = *(const short8*)&Bl[wn * 64 + ni * 16 + l][kk];
#pragma unroll
      for (int mi = 0; mi < 4; mi++)
#pragma unroll
        for (int ni = 0; ni < 4; ni++)
          acc[mi][ni] = __builtin_amdgcn_mfma_f32_16x16x32_bf16(af[mi], bfv[ni], acc[mi][ni], 0, 0, 0);
    }
    __syncthreads();
  }
  // epilogue: + b_i, store bf16 to gx[t][n][b]
  for (int ni = 0; ni < 4; ni++) {
    const int n = n0 + wn * 64 + ni * 16 + l;     // C col = lane&15
    const float bi = bias_c[n];
    for (int mi = 0; mi < 4; mi++) {
#pragma unroll
      for (int rr = 0; rr < 4; rr++) {            // C row = q*4 + rr
        const int rloc = wm * 64 + mi * 16 + q * 4 + rr;
        const int b = rloc >> 2, dt = rloc & 3;
        gx[((size_t)(t0 + dt) * H3 + n) * B_ + b] = f2bf(acc[mi][ni][rr] + bi);
      }
    }
  }
}

// ---------------------------------------------------------------- K2: recurrence
// 64 wgs x 256 thr, all co-resident (151KB LDS -> 1 wg/CU). wg g owns units
// [16g,16g+16). h exchange: hbuf[2][512][32] u64, word = tag | 2 bf16
// (unit pair 2j,2j+1 for batch b). h(t) -> buf[t&1], tag t+2. Consumer at
// step t reads buf[(t+1)&1], wants tag t+1. All loads/stores relaxed agent
// atomics -> no fences, no flags, no release drains. 4-wave K-split, P reduce
// in LDS double-buffered -> exactly one __syncthreads per step.
__global__ __launch_bounds__(256, 1) void gru_recur(
    const int* __restrict__ x, const void* __restrict__ hidden,
    const u16* __restrict__ Rt, const float* __restrict__ bias_c,
    const u16* __restrict__ gx, ull* __restrict__ hbuf,
    void* __restrict__ out, const int* dflag) {
  extern __shared__ char smem[];
  u16* Rl = (u16*)smem;                              // [48][1032] bf16, 99072 B
  float* P = (float*)(smem + 99072);                 // [2][4][32][49] f32, 50176 B
  unsigned* mw = (unsigned*)(smem + 99072 + 50176);  // [512] mask words, 2048 B
  const int f32o = *dflag;
  const int g = blockIdx.x, tid = threadIdx.x;
  const int lane = tid & 63, w = tid >> 6;
  const int l = lane & 15, q = lane >> 4;
  float* outf = (float*)out;
  u16* outb = (u16*)out;

  // stage R slice transposed: Rl[cc][k], cc = c*16+u <-> global row c*1024+16g+u
  for (int i = tid; i < 48 * 128; i += 256) {
    const int cc = i >> 7, ch = i & 127;
    const int c = cc >> 4, u = cc & 15;
    *(short8*)&Rl[cc * 1032 + ch * 8] =
        *(const short8*)(Rt + (size_t)(c * H_ + g * UPG + u) * H_ + ch * 8);
  }
  for (int i = tid; i < 512; i += 256) mw[i] = 0u;
  __syncthreads();
  for (int i = tid; i < B_ * T_; i += 256) {         // mask bits: mw[t] bit b
    const int b = i >> 9, t = i & 511;
    if (x[i] != 0) atomicOr(&mw[t], 1u << b);
  }

  // per-thread gate state: thread (b, up) owns ADJACENT units 2up, 2up+1
  // (pairing matches the u64 atom layout).
  const int b = tid & 31, up = tid >> 5;
  const int col0 = g * UPG + 2 * up;
  float br[2][3], hp[2];
#pragma unroll
  for (int p = 0; p < 2; p++) {
    const int col = col0 + p;
    br[p][0] = bias_c[H3 + col];
    br[p][1] = bias_c[H3 + H_ + col];
    br[p][2] = bias_c[H3 + 2 * H_ + col];
    hp[p] = ldf(hidden, (size_t)b * H_ + col, f32o);
  }
  // publish h(-1) into buf1 with tag 1 (poison 0xAAAA.. / zero never match)
  atomST(&hbuf[16384 + (size_t)(g * 8 + up) * 32 + b], packh(1u, hp[0], hp[1]));
  __syncthreads();   // Rl + mw staged before any wave computes

  for (int t = 0; t < T_; t++) {
    // gx prefetch (h-independent, oldest in VMEM queue)
    float gxv[2][3];
#pragma unroll
    for (int p = 0; p < 2; p++) {
      const int col = col0 + p;
#pragma unroll
      for (int c = 0; c < 3; c++)
        gxv[p][c] = bf2f(gx[((size_t)t * H3 + c * H_ + col) * B_ + b]);
    }

    // --- A phase: self-validating tagged loads of h(t-1) -------------------
    const ull* hb = hbuf + (size_t)((t + 1) & 1) * 16384;   // [512][32] u64
    const unsigned tg = (unsigned)(t + 1);                  // tag of h(t-1)
    const int jb0 = w * 128 + q * 4;                        // unit-pair base
    ull va[8][8];   // [kk][0..3]=b-row l, [4..7]=b-row 16+l
#pragma unroll
    for (int kk = 0; kk < 8; kk++) {
      const ull* p = hb + (size_t)(jb0 + kk * 16) * 32 + l;
#pragma unroll
      for (int i = 0; i < 4; i++) {
        va[kk][i]     = atomLD(p + i * 32);
        va[kk][4 + i] = atomLD(p + i * 32 + 16);
      }
    }
    while (1) {   // validate all chunks; re-issue only stale ones, per round
      int anybad = 0;
#pragma unroll
      for (int kk = 0; kk < 8; kk++) {
        int ok = 1;
#pragma unroll
        for (int i = 0; i < 8; i++) ok &= ((unsigned)(va[kk][i] >> 32) == tg);
        if (!__all(ok)) {
          anybad = 1;
          const ull* p = hb + (size_t)(jb0 + kk * 16) * 32 + l;
#pragma unroll
          for (int i = 0; i < 4; i++) {
            va[kk][i]     = atomLD(p + i * 32);
            va[kk][4 + i] = atomLD(p + i * 32 + 16);
          }
        }
      }
      if (!anybad) break;
      __builtin_amdgcn_s_sleep(1);
    }

    // --- gh partial GEMM: wave w covers k in [w*256, w*256+256) ------------
    float4_ acc[2][3];
#pragma unroll
    for (int mt = 0; mt < 2; mt++)
#pragma unroll
      for (int nt = 0; nt < 3; nt++) acc[mt][nt] = (float4_)0.0f;
#pragma unroll
    for (int kk = 0; kk < 8; kk++) {
      const int k = w * 256 + kk * 32 + q * 8;
      union { int4_ d; short8 s; } ua, ub;
#pragma unroll
      for (int i = 0; i < 4; i++) {
        ua.d[i] = (int)(unsigned)va[kk][i];        // low dword = packed bf16 pair
        ub.d[i] = (int)(unsigned)va[kk][4 + i];
      }
      const short8 a0 = ua.s, a1 = ub.s;
      const short8 r0 = *(const short8*)&Rl[(0 * 16 + l) * 1032 + k];
      const short8 r1 = *(const short8*)&Rl[(1 * 16 + l) * 1032 + k];
      const short8 r2 = *(const short8*)&Rl[(2 * 16 + l) * 1032 + k];
      acc[0][0] = __builtin_amdgcn_mfma_f32_16x16x32_bf16(a0, r0, acc[0][0], 0, 0, 0);
      acc[0][1] = __builtin_amdgcn_mfma_f32_16x16x32_bf16(a0, r1, acc[0][1], 0, 0, 0);
      acc[0][2] = __builtin_amdgcn_mfma_f32_16x16x32_bf16(a0, r2, acc[0][2], 0, 0, 0);
      acc[1][0] = __builtin_amdgcn_mfma_f32_16x16x32_bf16(a1, r0, acc[1][0], 0, 0, 0);
      acc[1][1] = __builtin_amdgcn_mfma_f32_16x16x32_bf16(a1, r1, acc[1][1], 0, 0, 0);
      acc[1][2] = __builtin_amdgcn_mfma_f32_16x16x32_bf16(a1, r2, acc[1][2], 0, 0, 0);
    }
    float* Pc = P + (t & 1) * 6272;   // double-buffered reduce scratch
#pragma unroll
    for (int mt = 0; mt < 2; mt++)
#pragma unroll
      for (int nt = 0; nt < 3; nt++)
#pragma unroll
        for (int rr = 0; rr < 4; rr++)
          Pc[w * 1568 + (mt * 16 + q * 4 + rr) * 49 + nt * 16 + l] = acc[mt][nt][rr];
    __syncthreads();   // the ONLY barrier per step (P[t&1] ready)

    // --- gates for (b, 2up) and (b, 2up+1) ---------------------------------
    const unsigned mword = mw[t];
#pragma unroll
    for (int p = 0; p < 2; p++) {
      const int u = 2 * up + p;
      float hz = 0.f, hr = 0.f, hn = 0.f;
#pragma unroll
      for (int ww = 0; ww < 4; ww++) {
        const float* Pb = Pc + ww * 1568 + b * 49;
        hz += Pb[u]; hr += Pb[16 + u]; hn += Pb[32 + u];
      }
      hz += br[p][0]; hr += br[p][1]; hn += br[p][2];
      const float z = 1.f / (1.f + __expf(-(gxv[p][0] + hz)));
      const float r = 1.f / (1.f + __expf(-(gxv[p][1] + hr)));
      float nn = gxv[p][2] + r * hn;
      nn = fminf(fmaxf(nn, -15.f), 15.f);
      const float e2 = __expf(2.f * nn);
      const float th = (e2 - 1.f) / (e2 + 1.f);
      float hnew = z * hp[p] + (1.f - z) * th;
      if (!((mword >> b) & 1u)) hnew = hp[p];    // masked: carry state
      hp[p] = hnew;
    }
    // publish h(t): single fire-and-forget tagged atom (no drains, no fence)
    atomST(&hbuf[(size_t)(t & 1) * 16384 + (size_t)(g * 8 + up) * 32 + b],
           packh((unsigned)(t + 2), hp[0], hp[1]));
    // output (off every ordering path; nontemporal, paired)
    const size_t oi = ((size_t)b * T_ + t) * H_ + col0;
    if (f32o) {
      __builtin_nontemporal_store(hp[0], outf + oi);
      __builtin_nontemporal_store(hp[1], outf + oi + 1);
    } else {
      const unsigned pw = ((unsigned)f2bf(hp[1]) << 16) | (unsigned)f2bf(hp[0]);
      __builtin_nontemporal_store(pw, (unsigned*)(outb + oi));
    }
  }
  // final state output
  {
    const size_t oi = (size_t)B_ * T_ * H_ + (size_t)b * H_ + col0;
    if (f32o) {
      __builtin_nontemporal_store(hp[0], outf + oi);
      __builtin_nontemporal_store(hp[1], outf + oi + 1);
    } else {
      const unsigned pw = ((unsigned)f2bf(hp[1]) << 16) | (unsigned)f2bf(hp[0]);
      __builtin_nontemporal_store(pw, (unsigned*)(outb + oi));
    }
  }
}

// ---------------------------------------------------------------- launch
extern "C" void kernel_launch(void* const* d_in, const int* in_sizes, int n_in,
                              void* d_out, int out_size, void* d_ws, size_t ws_size,
                              hipStream_t stream) {
  const int* x       = (const int*)d_in[0];
  const void* hidden = d_in[1];
  const void* emb    = d_in[2];
  const void* W      = d_in[3];
  const void* R      = d_in[4];
  const void* bias   = d_in[5];
  char* ws = (char*)d_ws;
  // ws map (bytes):
  u16*   gx      = (u16*)ws;                         // 100,663,296
  u16*   Wt      = (u16*)(ws + 100663296);           //   6,291,456
  u16*   Rt      = (u16*)(ws + 106954752);           //   6,291,456
  ull*   hbuf    = (ull*)(ws + 113246208);           //     262,144  [2][512][32] u64
  int*   dflag   = (int*)(ws + 113508352);           //         256
  float* bias_c  = (float*)(ws + 113508608);         //      24,576  (tot 113,533,184)

  hipLaunchKernelGGL(detect_norm, dim3(1), dim3(256), 0, stream,
                     emb, bias, dflag, bias_c);
  hipLaunchKernelGGL(transpose_kernel, dim3(32, 96, 2), dim3(256), 0, stream,
                     W, R, Wt, Rt, dflag);
  hipLaunchKernelGGL(gx_gemm, dim3(24, 128), dim3(256), 0, stream,
                     x, emb, Wt, bias_c, gx, dflag);
  // 151,296 B dynamic LDS (>64KB): set attribute every call (idempotent, capture-safe)
  hipFuncSetAttribute((const void*)gru_recur, hipFuncAttributeMaxDynamicSharedMemorySize, 151296);
  hipLaunchKernelGGL(gru_recur, dim3(NG), dim3(256), 151296, stream,
                     x, hidden, Rt, bias_c, gx, hbuf, d_out, dflag);
}

// Round 4
// 2734.518 us; speedup vs baseline: 1.7379x; 1.1034x over previous
//
#include <hip/hip_runtime.h>
#include <hip/hip_bf16.h>
#include <math.h>

// GRU encoder: B=32, T=512, V=32000, H=1024, reset_after=True, mask_zero=True.
//
// R6: retreat to the proven R3 structure (R4/R5 crashed; common denominator
// was new inline-asm primitives + ws overlays — all removed). Delta vs R3:
// EPOCH-VALIDATED TAGLESS h exchange, builtins only.
//   - hdat[2][512][32] u32: pure payload (2x bf16 per atom, 100% density).
//     Line traffic per wg per step halves (131KB -> 64KB; 8.4 -> 4.2 MB/step
//     chip-wide), va registers halve (128 -> 64 VGPRs), and the ~100 VALU
//     ops/thread/step of tag validation disappear.
//   - ep[2][256] u32 per-wave epochs: producer wave stores its data atoms,
//     __builtin_amdgcn_s_waitcnt(0) drains its own stores (they are
//     agent-scope sc1 atomics -> completed means L3-visible), then one lane
//     stores ep = t+2. Consumers spin on the 1KB epoch array (exact match
//     t+1; atomic loads are never speculated by LLVM, + sched_barrier(0)),
//     then issue tagless data loads. Same 2-parity flow control as R3 =>
//     awaited values survive until consumed; no deadlock, no overwrite race.
//   - detect_norm zeroes ep[] with agent-scope atomic stores: no cross-launch
//     residue can match (also closes R3's latent t=511 stale-tag race).
//   - P-reduce LDS stride 49->50: ds_write conflicts 4-way -> 2-way (free).
// No inline asm. ws map byte-identical to R3. One __syncthreads per step.

#define B_  32
#define T_  512
#define H_  1024
#define H3  3072
#define NG  64     // recurrence workgroups
#define UPG 16     // hidden units per wg

typedef short short8 __attribute__((ext_vector_type(8)));
typedef float float4_ __attribute__((ext_vector_type(4)));
typedef int   int4_  __attribute__((ext_vector_type(4)));
typedef unsigned short u16;
typedef unsigned int u32;

__device__ __forceinline__ float bf2f(u16 u) {
  union { unsigned i; float f; } v; v.i = ((unsigned)u) << 16; return v.f;
}
__device__ __forceinline__ u16 f2bf(float f) {   // round-to-nearest-even
  union { float f; unsigned i; } v; v.f = f;
  unsigned r = v.i + 0x7FFFu + ((v.i >> 16) & 1u);
  return (u16)(r >> 16);
}
__device__ __forceinline__ float ldf(const void* p, size_t i, int f32) {
  return f32 ? ((const float*)p)[i] : bf2f(((const u16*)p)[i]);
}
// 8 consecutive elements -> bf16 bits
__device__ __forceinline__ short8 ld8(const void* base, size_t off, int f32) {
  short8 r;
  if (f32) {
    const float* p = (const float*)base + off;
    float4_ a = *(const float4_*)p;
    float4_ b = *(const float4_*)(p + 4);
    r[0]=(short)f2bf(a[0]); r[1]=(short)f2bf(a[1]); r[2]=(short)f2bf(a[2]); r[3]=(short)f2bf(a[3]);
    r[4]=(short)f2bf(b[0]); r[5]=(short)f2bf(b[1]); r[6]=(short)f2bf(b[2]); r[7]=(short)f2bf(b[3]);
  } else {
    r = *(const short8*)((const u16*)base + off);
  }
  return r;
}

__device__ __forceinline__ u32 aload32(const u32* p) {   // device scope (L3)
  return __hip_atomic_load((u32*)p, __ATOMIC_RELAXED, __HIP_MEMORY_SCOPE_AGENT);
}
__device__ __forceinline__ void astore32(u32* p, u32 v) { // device scope (L3)
  __hip_atomic_store(p, v, __ATOMIC_RELAXED, __HIP_MEMORY_SCOPE_AGENT);
}
__device__ __forceinline__ u32 pack2(float h0, float h1) {
  return ((u32)f2bf(h1) << 16) | (u32)f2bf(h0);
}

// ------------------------------------------------------- Kd: dtype detect + canon
// Low u16 of each u32 word: fp32 -> uniform mantissa bits, P(bits[14:7]>=128)~0.5;
// packed bf16 -> a valid ~N(0,0.02) bf16, exponent field < 128 always.
__global__ __launch_bounds__(256) void detect_norm(
    const void* __restrict__ emb, const void* __restrict__ bias,
    int* dflag, float* __restrict__ bias_c, u32* __restrict__ ep) {
  __shared__ int cnt;
  __shared__ int sflag;
  if (threadIdx.x == 0) cnt = 0;
  __syncthreads();
  const unsigned* e = (const unsigned*)emb;
  const unsigned lo = e[threadIdx.x] & 0xFFFFu;
  if (((lo >> 7) & 0xFFu) >= 128u) atomicAdd(&cnt, 1);
  __syncthreads();
  if (threadIdx.x == 0) {
    sflag = (cnt > 32) ? 1 : 0;    // fp32 ~128 hits, bf16-packed ~0
    *dflag = sflag;
  }
  __syncthreads();
  const int f32 = sflag;
  for (int i = threadIdx.x; i < 2 * H3; i += 256) bias_c[i] = ldf(bias, i, f32);
  // zero both epoch parities with agent-scope atomic (sc1) stores: visible to
  // gru_recur's sc1 spin loads; kernel-boundary ordering guarantees these land
  // first. No cross-launch residue can ever equal an awaited epoch.
  astore32(&ep[threadIdx.x], 0u);
  astore32(&ep[threadIdx.x + 256], 0u);
}

// ---------------------------------------------------------------- K0: transpose
// [1024][3072] -> [3072][1024] canonical bf16, for both W and R. 32x32 tiles.
__global__ __launch_bounds__(256) void transpose_kernel(
    const void* __restrict__ W, const void* __restrict__ R,
    u16* __restrict__ Wt, u16* __restrict__ Rt, const int* dflag) {
  __shared__ u16 tile[32][33];
  const int f32 = *dflag;
  const void* src = blockIdx.z ? R : W;
  u16* dst = blockIdx.z ? Rt : Wt;
  int k0 = blockIdx.x * 32, n0 = blockIdx.y * 32;
  int c = threadIdx.x & 31, r8 = threadIdx.x >> 5;
  for (int rr = r8; rr < 32; rr += 8)
    tile[rr][c] = f2bf(ldf(src, (size_t)(k0 + rr) * H3 + n0 + c, f32));
  __syncthreads();
  for (int rr = r8; rr < 32; rr += 8)
    dst[(size_t)(n0 + rr) * H_ + k0 + c] = tile[c][rr];
}

// ---------------------------------------------------------------- K1: gx GEMM
// Tile: 128 rows (32 b x 4 t) x 128 n, BK=64. 4 waves, each 64x64 via 4x4 MFMA.
__global__ __launch_bounds__(256) void gx_gemm(
    const int* __restrict__ x, const void* __restrict__ emb,
    const u16* __restrict__ Wt, const float* __restrict__ bias_c,
    u16* __restrict__ gx, const int* dflag) {
  __shared__ u16 Al[128][72];   // A[m][k], +8 pad
  __shared__ u16 Bl[128][72];   // B^T: [n][k]
  __shared__ int tok[128];
  const int f32 = *dflag;
  const int tid = threadIdx.x;
  const int n0 = blockIdx.x * 128;
  const int t0 = blockIdx.y * 4;
  if (tid < 128) { int b = tid >> 2, dt = tid & 3; tok[tid] = x[b * T_ + t0 + dt]; }
  __syncthreads();
  const int lane = tid & 63, w = tid >> 6;
  const int l = lane & 15, q = lane >> 4;
  const int wm = w >> 1, wn = w & 1;
  float4_ acc[4][4];
  for (int i = 0; i < 4; i++) for (int j = 0; j < 4; j++) acc[i][j] = (float4_)0.0f;
  const int row = tid >> 1, half = tid & 1;
  for (int k0 = 0; k0 < H_; k0 += 64) {
    const size_t offA = (size_t)tok[row] * H_ + k0 + half * 32;
    const u16* srcB = Wt + (size_t)(n0 + row) * H_ + k0 + half * 32;
#pragma unroll
    for (int c = 0; c < 4; c++) {
      *(short8*)&Al[row][half * 32 + c * 8] = ld8(emb, offA + c * 8, f32);
      *(short8*)&Bl[row][half * 32 + c * 8] = *(const short8*)(srcB + c * 8);
    }
    __syncthreads();
#pragma unroll
    for (int ks = 0; ks < 2; ks++) {
      const int kk = ks * 32 + q * 8;
      short8 af[4], bfv[4];
#pragma unroll
      for (int mi = 0; mi < 4; mi++) af[mi] = *(const short8*)&Al[wm * 64 + mi * 16 + l][kk];
#pragma unroll
      for (int ni = 0; ni < 4; ni++) bfv[ni] = *(const short8*)&Bl[wn * 64 + ni * 16 + l][kk];
#pragma unroll
      for (int mi = 0; mi < 4; mi++)
#pragma unroll
        for (int ni = 0; ni < 4; ni++)
          acc[mi][ni] = __builtin_amdgcn_mfma_f32_16x16x32_bf16(af[mi], bfv[ni], acc[mi][ni], 0, 0, 0);
    }
    __syncthreads();
  }
  // epilogue: + b_i, store bf16 to gx[t][n][b]
  for (int ni = 0; ni < 4; ni++) {
    const int n = n0 + wn * 64 + ni * 16 + l;     // C col = lane&15
    const float bi = bias_c[n];
    for (int mi = 0; mi < 4; mi++) {
#pragma unroll
      for (int rr = 0; rr < 4; rr++) {            // C row = q*4 + rr
        const int rloc = wm * 64 + mi * 16 + q * 4 + rr;
        const int b = rloc >> 2, dt = rloc & 3;
        gx[((size_t)(t0 + dt) * H3 + n) * B_ + b] = f2bf(acc[mi][ni][rr] + bi);
      }
    }
  }
}

// ---------------------------------------------------------------- K2: recurrence
// 64 wgs x 256 thr, all co-resident (152KB LDS -> 1 wg/CU). wg g owns units
// [16g,16g+16). h(t) payload -> hdat[t&1], per-wave epoch ep[t&1][g*4+w]=t+2
// published AFTER the wave's own data stores drain (s_waitcnt(0)). Consumer
// at step t spins on ep[(t+1)&1][*]==t+1 then reads tagless payload.
// One __syncthreads per step (P double-buffered by parity).
__global__ __launch_bounds__(256, 1) void gru_recur(
    const int* __restrict__ x, const void* __restrict__ hidden,
    const u16* __restrict__ Rt, const float* __restrict__ bias_c,
    const u16* __restrict__ gx, u32* __restrict__ hdat,
    u32* __restrict__ ep, void* __restrict__ out, const int* dflag) {
  extern __shared__ char smem[];
  u16* Rl = (u16*)smem;                              // [48][1032] bf16, 99072 B
  float* P = (float*)(smem + 99072);                 // [2][4][32][50] f32, 51200 B
  unsigned* mw = (unsigned*)(smem + 99072 + 51200);  // [512] mask words, 2048 B
  const int f32o = *dflag;
  const int g = blockIdx.x, tid = threadIdx.x;
  const int lane = tid & 63, w = tid >> 6;
  const int l = lane & 15, q = lane >> 4;
  float* outf = (float*)out;
  u16* outb = (u16*)out;

  // stage R slice transposed: Rl[cc][k], cc = c*16+u <-> global row c*1024+16g+u
  for (int i = tid; i < 48 * 128; i += 256) {
    const int cc = i >> 7, ch = i & 127;
    const int c = cc >> 4, u = cc & 15;
    *(short8*)&Rl[cc * 1032 + ch * 8] =
        *(const short8*)(Rt + (size_t)(c * H_ + g * UPG + u) * H_ + ch * 8);
  }
  for (int i = tid; i < 512; i += 256) mw[i] = 0u;
  __syncthreads();
  for (int i = tid; i < B_ * T_; i += 256) {         // mask bits: mw[t] bit b
    const int b = i >> 9, t = i & 511;
    if (x[i] != 0) atomicOr(&mw[t], 1u << b);
  }

  // per-thread gate state: thread (b, up) owns ADJACENT units 2up, 2up+1
  const int b = tid & 31, up = tid >> 5;
  const int col0 = g * UPG + 2 * up;
  float br[2][3], hp[2];
#pragma unroll
  for (int p = 0; p < 2; p++) {
    const int col = col0 + p;
    br[p][0] = bias_c[H3 + col];
    br[p][1] = bias_c[H3 + H_ + col];
    br[p][2] = bias_c[H3 + 2 * H_ + col];
    hp[p] = ldf(hidden, (size_t)b * H_ + col, f32o);
  }
  // entry publish: h(-1) payload -> parity 1, then drain, then epoch = 1
  astore32(&hdat[16384 + (size_t)(g * 8 + up) * 32 + b], pack2(hp[0], hp[1]));
  __builtin_amdgcn_s_waitcnt(0);
  __builtin_amdgcn_sched_barrier(0);
  if ((tid & 63) == 0) astore32(&ep[256 + g * 4 + w], 1u);
  __syncthreads();   // Rl + mw staged before any wave computes

  for (int t = 0; t < T_; t++) {
    // gx prefetch (h-independent, oldest in VMEM queue)
    float gxv[2][3];
#pragma unroll
    for (int p = 0; p < 2; p++) {
      const int col = col0 + p;
#pragma unroll
      for (int c = 0; c < 3; c++)
        gxv[p][c] = bf2f(gx[((size_t)t * H3 + c * H_ + col) * B_ + b]);
    }

    // --- epoch spin: all 256 producer-wave epochs must equal t+1 -----------
    const u32 aw = (u32)(t + 1);
    const u32* epp = ep + (size_t)((t + 1) & 1) * 256;
    const int lid = lane;
    while (1) {
      u32 e0 = aload32(epp + lid);
      u32 e1 = aload32(epp + lid + 64);
      u32 e2 = aload32(epp + lid + 128);
      u32 e3 = aload32(epp + lid + 192);
      if (__all(e0 == aw && e1 == aw && e2 == aw && e3 == aw)) break;
      __builtin_amdgcn_s_sleep(1);
    }
    __builtin_amdgcn_sched_barrier(0);

    // --- tagless payload loads: u32 = 2 bf16 units, 64 per thread ----------
    const u32* hd = hdat + (size_t)((t + 1) & 1) * 16384;   // [512][32] u32
    const int jb0 = w * 128 + q * 4;                        // unit-pair base
    u32 va[8][8];   // [kk][0..3]=b-row l, [4..7]=b-row 16+l
#pragma unroll
    for (int kk = 0; kk < 8; kk++) {
      const u32* p = hd + (size_t)(jb0 + kk * 16) * 32 + l;
#pragma unroll
      for (int i = 0; i < 4; i++) {
        va[kk][i]     = aload32(p + i * 32);
        va[kk][4 + i] = aload32(p + i * 32 + 16);
      }
    }

    // --- gh partial GEMM: wave w covers k in [w*256, w*256+256) ------------
    float4_ acc[2][3];
#pragma unroll
    for (int mt = 0; mt < 2; mt++)
#pragma unroll
      for (int nt = 0; nt < 3; nt++) acc[mt][nt] = (float4_)0.0f;
#pragma unroll
    for (int kk = 0; kk < 8; kk++) {
      const int k = w * 256 + kk * 32 + q * 8;
      union { int4_ d; short8 s; } ua, ub;
#pragma unroll
      for (int i = 0; i < 4; i++) {
        ua.d[i] = (int)va[kk][i];        // 2 packed bf16 units
        ub.d[i] = (int)va[kk][4 + i];
      }
      const short8 a0 = ua.s, a1 = ub.s;
      const short8 r0 = *(const short8*)&Rl[(0 * 16 + l) * 1032 + k];
      const short8 r1 = *(const short8*)&Rl[(1 * 16 + l) * 1032 + k];
      const short8 r2 = *(const short8*)&Rl[(2 * 16 + l) * 1032 + k];
      acc[0][0] = __builtin_amdgcn_mfma_f32_16x16x32_bf16(a0, r0, acc[0][0], 0, 0, 0);
      acc[0][1] = __builtin_amdgcn_mfma_f32_16x16x32_bf16(a0, r1, acc[0][1], 0, 0, 0);
      acc[0][2] = __builtin_amdgcn_mfma_f32_16x16x32_bf16(a0, r2, acc[0][2], 0, 0, 0);
      acc[1][0] = __builtin_amdgcn_mfma_f32_16x16x32_bf16(a1, r0, acc[1][0], 0, 0, 0);
      acc[1][1] = __builtin_amdgcn_mfma_f32_16x16x32_bf16(a1, r1, acc[1][1], 0, 0, 0);
      acc[1][2] = __builtin_amdgcn_mfma_f32_16x16x32_bf16(a1, r2, acc[1][2], 0, 0, 0);
    }
    float* Pc = P + (t & 1) * 6400;   // double-buffered reduce scratch
#pragma unroll
    for (int mt = 0; mt < 2; mt++)
#pragma unroll
      for (int nt = 0; nt < 3; nt++)
#pragma unroll
        for (int rr = 0; rr < 4; rr++)
          Pc[w * 1600 + (mt * 16 + q * 4 + rr) * 50 + nt * 16 + l] = acc[mt][nt][rr];
    __syncthreads();   // the ONLY barrier per step (P[t&1] ready)

    // --- gates for (b, 2up) and (b, 2up+1) ---------------------------------
    const unsigned mword = mw[t];
#pragma unroll
    for (int p = 0; p < 2; p++) {
      const int u = 2 * up + p;
      float hz = 0.f, hr = 0.f, hn = 0.f;
#pragma unroll
      for (int ww = 0; ww < 4; ww++) {
        const float* Pb = Pc + ww * 1600 + b * 50;
        hz += Pb[u]; hr += Pb[16 + u]; hn += Pb[32 + u];
      }
      hz += br[p][0]; hr += br[p][1]; hn += br[p][2];
      const float z = 1.f / (1.f + __expf(-(gxv[p][0] + hz)));
      const float r = 1.f / (1.f + __expf(-(gxv[p][1] + hr)));
      float nn = gxv[p][2] + r * hn;
      nn = fminf(fmaxf(nn, -15.f), 15.f);
      const float e2 = __expf(2.f * nn);
      const float th = (e2 - 1.f) / (e2 + 1.f);
      float hnew = z * hp[p] + (1.f - z) * th;
      if (!((mword >> b) & 1u)) hnew = hp[p];    // masked: carry state
      hp[p] = hnew;
    }
    // publish h(t): payload store -> own-wave drain -> per-wave epoch
    astore32(&hdat[(size_t)(t & 1) * 16384 + (size_t)(g * 8 + up) * 32 + b],
             pack2(hp[0], hp[1]));
    __builtin_amdgcn_s_waitcnt(0);
    __builtin_amdgcn_sched_barrier(0);
    if ((tid & 63) == 0) astore32(&ep[(size_t)(t & 1) * 256 + g * 4 + w], (u32)(t + 2));
    // output (after the epoch publish; off the critical sync path)
    const size_t oi = ((size_t)b * T_ + t) * H_ + col0;
    if (f32o) {
      __builtin_nontemporal_store(hp[0], outf + oi);
      __builtin_nontemporal_store(hp[1], outf + oi + 1);
    } else {
      const unsigned pw = ((unsigned)f2bf(hp[1]) << 16) | (unsigned)f2bf(hp[0]);
      __builtin_nontemporal_store(pw, (unsigned*)(outb + oi));
    }
  }
  // final state output
  {
    const size_t oi = (size_t)B_ * T_ * H_ + (size_t)b * H_ + col0;
    if (f32o) {
      __builtin_nontemporal_store(hp[0], outf + oi);
      __builtin_nontemporal_store(hp[1], outf + oi + 1);
    } else {
      const unsigned pw = ((unsigned)f2bf(hp[1]) << 16) | (unsigned)f2bf(hp[0]);
      __builtin_nontemporal_store(pw, (unsigned*)(outb + oi));
    }
  }
}

// ---------------------------------------------------------------- launch
extern "C" void kernel_launch(void* const* d_in, const int* in_sizes, int n_in,
                              void* d_out, int out_size, void* d_ws, size_t ws_size,
                              hipStream_t stream) {
  const int* x       = (const int*)d_in[0];
  const void* hidden = d_in[1];
  const void* emb    = d_in[2];
  const void* W      = d_in[3];
  const void* R      = d_in[4];
  const void* bias   = d_in[5];
  char* ws = (char*)d_ws;
  // ws map (bytes) — byte-identical envelope to the proven R3 map:
  u16*   gx      = (u16*)ws;                         // 100,663,296
  u16*   Wt      = (u16*)(ws + 100663296);           //   6,291,456
  u16*   Rt      = (u16*)(ws + 106954752);           //   6,291,456
  u32*   hdat    = (u32*)(ws + 113246208);           //     131,072  [2][512][32] u32
  u32*   ep      = (u32*)(ws + 113246208 + 131072);  //       2,048  [2][256] u32
  int*   dflag   = (int*)(ws + 113508352);           //         256
  float* bias_c  = (float*)(ws + 113508608);         //      24,576  (tot 113,533,184)

  hipLaunchKernelGGL(detect_norm, dim3(1), dim3(256), 0, stream,
                     emb, bias, dflag, bias_c, ep);
  hipLaunchKernelGGL(transpose_kernel, dim3(32, 96, 2), dim3(256), 0, stream,
                     W, R, Wt, Rt, dflag);
  hipLaunchKernelGGL(gx_gemm, dim3(24, 128), dim3(256), 0, stream,
                     x, emb, Wt, bias_c, gx, dflag);
  // 152,320 B dynamic LDS (>64KB): set attribute every call (idempotent, capture-safe)
  hipFuncSetAttribute((const void*)gru_recur, hipFuncAttributeMaxDynamicSharedMemorySize, 152320);
  hipLaunchKernelGGL(gru_recur, dim3(NG), dim3(256), 152320, stream,
                     x, hidden, Rt, bias_c, gx, hdat, ep, d_out, dflag);
}